// Round 3
// baseline (242.656 us; speedup 1.0000x reference)
//
#include <hip/hip_runtime.h>
#include <stdint.h>

// E=512, H=8, D=64, B=4, Nq=Nk=2048
// bf16 MFMA pipeline: cvt -> QKV proj GEMM (Q pre-scaled) -> flash attn
// (masked via MFMA C-in, KV-split x4 per block, LDS combine) -> out proj GEMM

typedef __attribute__((ext_vector_type(8))) short bf16x8;  // 8 bf16 in 4 VGPRs
typedef __attribute__((ext_vector_type(4))) float f32x4;

#define SCLQ 0.18033688011112042f  // 0.125 * log2(e): logits emerge in log2 domain

static __device__ __forceinline__ unsigned short f2bf(float f) {
    union { float f; unsigned u; } x; x.f = f;
    unsigned r = x.u + 0x7fffu + ((x.u >> 16) & 1u);  // RTN-even
    return (unsigned short)(r >> 16);
}

static __device__ __forceinline__ f32x4 mfma16(bf16x8 a, bf16x8 b, f32x4 c) {
    return __builtin_amdgcn_mfma_f32_16x16x32_bf16(a, b, c, 0, 0, 0);
}

#define GLOAD_LDS16(g, l)                                                            \
    __builtin_amdgcn_global_load_lds((const __attribute__((address_space(1))) void*)(g), \
                                     (__attribute__((address_space(3))) void*)(l), 16, 0, 0)

// ---------------- conversion kernels ----------------

__global__ __launch_bounds__(256) void cvt_x_kernel(
    const float* __restrict__ xq, const float* __restrict__ xk, const float* __restrict__ xv,
    short* __restrict__ oq, short* __restrict__ ok, short* __restrict__ ov)
{
    const float* src = (blockIdx.y == 0) ? xq : (blockIdx.y == 1) ? xk : xv;
    short* dst = (blockIdx.y == 0) ? oq : (blockIdx.y == 1) ? ok : ov;
    size_t i = (size_t)blockIdx.x * 256 + threadIdx.x;
    float4 v = ((const float4*)src)[i];
    short4 o;
    o.x = (short)f2bf(v.x); o.y = (short)f2bf(v.y);
    o.z = (short)f2bf(v.z); o.w = (short)f2bf(v.w);
    ((short4*)dst)[i] = o;
}

__global__ __launch_bounds__(256) void cvt_wt_kernel(
    const float* __restrict__ Wq, const float* __restrict__ Wk,
    const float* __restrict__ Wv, const float* __restrict__ Wo,
    short* __restrict__ WqT, short* __restrict__ WkT,
    short* __restrict__ WvT, short* __restrict__ WoT)
{
    int z = blockIdx.y;
    const float* W = (z == 0) ? Wq : (z == 1) ? Wk : (z == 2) ? Wv : Wo;
    short* WT = (z == 0) ? WqT : (z == 1) ? WkT : (z == 2) ? WvT : WoT;
    int t = blockIdx.x * 256 + threadIdx.x;
    int n = t & 511;
    int k0 = (t >> 9) * 8;
    union { short s[8]; int4 v; } u;
#pragma unroll
    for (int j = 0; j < 8; ++j) u.s[j] = (short)f2bf(W[(size_t)(k0 + j) * 512 + n]);
    *(int4*)(WT + (size_t)n * 512 + k0) = u.v;
}

// mask (4-byte elems, nonzero = keep) -> packed bits; word w covers k=[w*64,w*64+64)
__global__ __launch_bounds__(256) void pack_mask_kernel(
    const int* __restrict__ mask, unsigned long long* __restrict__ mp)
{
    int lane = threadIdx.x & 63;
    int row = blockIdx.x * 4 + (threadIdx.x >> 6);  // b*2048+q
    const int* mrow = mask + (size_t)row * 2048;
#pragma unroll 4
    for (int w = 0; w < 32; ++w) {
        unsigned long long bits = __ballot(mrow[w * 64 + lane] != 0);
        if (lane == 0) mp[(size_t)row * 32 + w] = bits;
    }
}

// ---------------- GEMM: C[8192x512] = A[8192x512] @ W  (+bias) ----------------
// mode 0: Q -> [b,h,tok,d] bf16, pre-scaled by 0.125*log2e ; 1: K -> [b,h,tok,d]
// mode 2: V -> [b,h,d,tok] bf16 ; 3: fp32 row-major out
__global__ __launch_bounds__(256) void gemm_kernel(
    const short* __restrict__ A, const short* __restrict__ BT,
    const float* __restrict__ bias, void* __restrict__ Cout, int mode)
{
    __shared__ char lds[32768];
    const int tid = threadIdx.x;
    const int lane = tid & 63;
    const int wid = tid >> 6;
    const int l15 = lane & 15, l4 = lane >> 4;
    const int m0 = blockIdx.y * 128;
    const int n0 = blockIdx.x * 128;
    const int wr = wid >> 1, wc = wid & 1;

    f32x4 zero = {0.f, 0.f, 0.f, 0.f};
    f32x4 acc[4][4];
#pragma unroll
    for (int i = 0; i < 4; ++i)
#pragma unroll
        for (int j = 0; j < 4; ++j) acc[i][j] = zero;

    char* Alds = lds;
    char* Blds = lds + 16384;

    for (int t = 0; t < 8; ++t) {
        const int k0 = t * 64;
#pragma unroll
        for (int s = 0; s < 4; ++s) {
            int p = s * 256 + tid;
            int r = p >> 3, c = p & 7;
            GLOAD_LDS16(A + (size_t)(m0 + r) * 512 + k0 + 8 * (c ^ (r & 7)),
                        Alds + s * 4096 + wid * 1024);
            GLOAD_LDS16(BT + (size_t)(n0 + r) * 512 + k0 + 8 * (c ^ (r & 7)),
                        Blds + s * 4096 + wid * 1024);
        }
        __syncthreads();
#pragma unroll
        for (int ks = 0; ks < 2; ++ks) {
            bf16x8 af[4], bfr[4];
#pragma unroll
            for (int mb = 0; mb < 4; ++mb) {
                int row = wr * 64 + mb * 16 + l15;
                af[mb] = *(const bf16x8*)(Alds + row * 128 +
                                          ((ks * 64 + l4 * 16) ^ ((row & 7) << 4)));
            }
#pragma unroll
            for (int nb = 0; nb < 4; ++nb) {
                int row = wc * 64 + nb * 16 + l15;
                bfr[nb] = *(const bf16x8*)(Blds + row * 128 +
                                           ((ks * 64 + l4 * 16) ^ ((row & 7) << 4)));
            }
#pragma unroll
            for (int mb = 0; mb < 4; ++mb)
#pragma unroll
                for (int nb = 0; nb < 4; ++nb)
                    acc[mb][nb] = mfma16(af[mb], bfr[nb], acc[mb][nb]);
        }
        __syncthreads();
    }

#pragma unroll
    for (int nb = 0; nb < 4; ++nb) {
        int n = n0 + wc * 64 + nb * 16 + l15;
        float bv = bias[n];
#pragma unroll
        for (int mb = 0; mb < 4; ++mb) {
#pragma unroll
            for (int r = 0; r < 4; ++r) {
                int m = m0 + wr * 64 + mb * 16 + l4 * 4 + r;
                float val = acc[mb][nb][r] + bv;
                if (mode == 0) val *= SCLQ;  // fold softmax scale+log2e into Q
                if (mode == 3) {
                    ((float*)Cout)[(size_t)m * 512 + n] = val;
                } else {
                    int b = m >> 11, tok = m & 2047;
                    int h = n >> 6, d = n & 63;
                    short* o = (short*)Cout;
                    if (mode == 2)
                        o[((size_t)(b * 8 + h) * 64 + d) * 2048 + tok] = (short)f2bf(val);
                    else
                        o[((size_t)(b * 8 + h) * 2048 + tok) * 64 + d] = (short)f2bf(val);
                }
            }
        }
    }
}

// ---------------- masked flash attention (KV-split x4, LDS combine) ----------------
// grid (64, 8, 4) = 2048 blocks; block owns 32 q-rows; wave w handles kv-tiles
// [w*8, w*8+8) of 64-wide KV blocks. Swapped QK^T (S^T: col=l15=q, row=l4*4+r=k);
// mask applied as MFMA C-init (0 / -1e30); Q pre-scaled so logits are log2-domain.
// After the loop: partial (m,l,O) -> LDS, barrier, 256-thread combine -> AO bf16.
__global__ __launch_bounds__(256, 3) void attn_kernel(
    const short* __restrict__ Q, const short* __restrict__ K,
    const short* __restrict__ VT, const unsigned long long* __restrict__ mp,
    short* __restrict__ AO)
{
    // LDS map: [0,16384): per-wave P buffers (phase 1, wid*4096)
    //          [0,33280): Of partials f32, stride 260 B/row (phase 2, overlaps P)
    //          [33280,34304): (m,l) float2 per (wave, q)
    __shared__ char lds[34304];
    const int lane = threadIdx.x & 63;
    const int wid = threadIdx.x >> 6;
    const int l15 = lane & 15, l4 = lane >> 4;
    const int b = blockIdx.z, h = blockIdx.y;
    const int q0 = blockIdx.x * 32;
    const size_t bh = (size_t)b * 8 + h;
    const short* Qp = Q + (bh * 2048 + q0) * 64;
    const short* Kp = K + (bh * 2048 + (size_t)wid * 512) * 64;  // wave's kv quarter
    const short* Vp = VT + bh * 64 * 2048;
    const int ktb = wid * 8;
    char* Pw = lds + wid * 4096;
    const int sw = (l15 & 7) << 4;  // per-row XOR swizzle (G4)

    // Q fragments (persistent): aq[qs][ds] = Q[q0+qs*16+l15][ds*32 + l4*8 + j]
    bf16x8 aq[2][2];
#pragma unroll
    for (int qs = 0; qs < 2; ++qs)
#pragma unroll
        for (int ds = 0; ds < 2; ++ds)
            aq[qs][ds] = *(const bf16x8*)(Qp + (qs * 16 + l15) * 64 + ds * 32 + l4 * 8);

    const f32x4 zero = {0.f, 0.f, 0.f, 0.f};
    f32x4 o[2][4];
    float mrun[2] = {-1e30f, -1e30f}, lrun[2] = {0.f, 0.f};
#pragma unroll
    for (int qs = 0; qs < 2; ++qs)
#pragma unroll
        for (int dt = 0; dt < 4; ++dt) o[qs][dt] = zero;

    const unsigned long long* mr0 = mp + ((size_t)b * 2048 + q0 + l15) * 32 + ktb;
    const unsigned long long* mr1 = mr0 + 16 * 32;

    // single-buffered K/V frags; prefetch issued after last consumer (WAR, in-order)
    bf16x8 kf[4][2], vf[4][2];
#pragma unroll
    for (int kb = 0; kb < 4; ++kb)
#pragma unroll
        for (int ds = 0; ds < 2; ++ds)
            kf[kb][ds] = *(const bf16x8*)(Kp + (kb * 16 + l15) * 64 + ds * 32 + l4 * 8);
#pragma unroll
    for (int dt = 0; dt < 4; ++dt)
#pragma unroll
        for (int ks = 0; ks < 2; ++ks)
            vf[dt][ks] = *(const bf16x8*)(Vp + (size_t)(dt * 16 + l15) * 2048 +
                                          ktb * 64 + ks * 32 + l4 * 8);
    unsigned long long mwq0 = mr0[0], mwq1 = mr1[0];
    unsigned long long mwn0 = 0, mwn1 = 0;

// QK^T with mask as C-init: sv[kb] = K*Q + (bit ? 0 : -1e30)
#define QKT_BLOCK(QS, MWQ)                                                        \
    {                                                                             \
        unsigned long long ms_ = (MWQ) >> (l4 * 4);                               \
        unsigned w0_ = (unsigned)ms_, w1_ = (unsigned)(ms_ >> 32);                \
        _Pragma("unroll") for (int kb = 0; kb < 4; ++kb) {                        \
            unsigned ws_ = (kb & 2) ? w1_ : w0_;                                  \
            f32x4 ini;                                                            \
            _Pragma("unroll") for (int r = 0; r < 4; ++r)                         \
                ini[r] = (ws_ & (1u << (((kb & 1) << 4) + r))) ? 0.f : -1e30f;    \
            sv[kb] = mfma16(kf[kb][1], aq[QS][1],                                 \
                            mfma16(kf[kb][0], aq[QS][0], ini));                   \
        }                                                                         \
    }

// tree max -> 2 shfl -> defer-max rescale -> exp2 -> pack -> swizzled P write
#define SM_BLOCK(QS)                                                              \
    {                                                                             \
        float pk0 = fmaxf(fmaxf(sv[0][0], sv[0][1]), fmaxf(sv[0][2], sv[0][3]));  \
        float pk1 = fmaxf(fmaxf(sv[1][0], sv[1][1]), fmaxf(sv[1][2], sv[1][3]));  \
        float pk2 = fmaxf(fmaxf(sv[2][0], sv[2][1]), fmaxf(sv[2][2], sv[2][3]));  \
        float pk3 = fmaxf(fmaxf(sv[3][0], sv[3][1]), fmaxf(sv[3][2], sv[3][3]));  \
        float pm = fmaxf(fmaxf(pk0, pk1), fmaxf(pk2, pk3));                       \
        pm = fmaxf(pm, __shfl_xor(pm, 16, 64));                                   \
        pm = fmaxf(pm, __shfl_xor(pm, 32, 64));                                   \
        if (__any(pm > mrun[QS] + 8.f)) {                                         \
            float mnew = fmaxf(mrun[QS], pm);                                     \
            float al = exp2f(mrun[QS] - mnew);                                    \
            mrun[QS] = mnew; lrun[QS] *= al;                                      \
            _Pragma("unroll") for (int r = 0; r < 4; ++r) {                       \
                float aR = __shfl(al, l4 * 4 + r, 64);                            \
                _Pragma("unroll") for (int dt = 0; dt < 4; ++dt)                  \
                    o[QS][dt][r] *= aR;                                           \
            }                                                                     \
        }                                                                         \
        float sk0, sk1, sk2, sk3;                                                 \
        _Pragma("unroll") for (int kb = 0; kb < 4; ++kb) {                        \
            float e0 = exp2f(sv[kb][0] - mrun[QS]);                               \
            float e1 = exp2f(sv[kb][1] - mrun[QS]);                               \
            float e2 = exp2f(sv[kb][2] - mrun[QS]);                               \
            float e3 = exp2f(sv[kb][3] - mrun[QS]);                               \
            float sk_ = (e0 + e1) + (e2 + e3);                                    \
            if (kb == 0) sk0 = sk_; else if (kb == 1) sk1 = sk_;                  \
            else if (kb == 2) sk2 = sk_; else sk3 = sk_;                          \
            unsigned u0, u1;                                                      \
            asm("v_cvt_pk_bf16_f32 %0, %1, %2" : "=v"(u0) : "v"(e0), "v"(e1));    \
            asm("v_cvt_pk_bf16_f32 %0, %1, %2" : "=v"(u1) : "v"(e2), "v"(e3));    \
            uint2 wv; wv.x = u0; wv.y = u1;                                       \
            *(uint2*)(Pw + (QS) * 2048 + l15 * 128 + ((kb * 32 + l4 * 8) ^ sw)) = wv; \
        }                                                                         \
        float ls = (sk0 + sk1) + (sk2 + sk3);                                     \
        ls += __shfl_xor(ls, 16, 64);                                             \
        ls += __shfl_xor(ls, 32, 64);                                             \
        lrun[QS] += ls;                                                           \
    }

#pragma unroll
    for (int lt = 0; lt < 8; ++lt) {
        f32x4 sv[4];
        QKT_BLOCK(0, mwq0)
        SM_BLOCK(0)
        QKT_BLOCK(1, mwq1)
        if (lt < 7) {  // K+mask prefetch for lt+1 (kf fully consumed above)
#pragma unroll
            for (int kb = 0; kb < 4; ++kb)
#pragma unroll
                for (int ds = 0; ds < 2; ++ds)
                    kf[kb][ds] = *(const bf16x8*)(Kp + ((lt + 1) * 64 + kb * 16 + l15) * 64 +
                                                  ds * 32 + l4 * 8);
            mwn0 = mr0[lt + 1]; mwn1 = mr1[lt + 1];
        }
        SM_BLOCK(1)
        asm volatile("s_waitcnt lgkmcnt(0)" ::: "memory");  // P writes visible to own wave
        // PV: A = P[q=l15][k contiguous], B = vf (col=l15=d)
#pragma unroll
        for (int qs = 0; qs < 2; ++qs)
#pragma unroll
            for (int ks = 0; ks < 2; ++ks) {
                bf16x8 ap = *(const bf16x8*)(Pw + qs * 2048 + l15 * 128 +
                                             ((ks * 64 + l4 * 16) ^ sw));
#pragma unroll
                for (int dt = 0; dt < 4; ++dt)
                    o[qs][dt] = mfma16(ap, vf[dt][ks], o[qs][dt]);
            }
        if (lt < 7) {  // V prefetch for lt+1 (vf fully consumed by PV above)
#pragma unroll
            for (int dt = 0; dt < 4; ++dt)
#pragma unroll
                for (int ks = 0; ks < 2; ++ks)
                    vf[dt][ks] = *(const bf16x8*)(Vp + (size_t)(dt * 16 + l15) * 2048 +
                                                  (ktb + lt + 1) * 64 + ks * 32 + l4 * 8);
            mwq0 = mwn0; mwq1 = mwn1;
        }
    }
#undef QKT_BLOCK
#undef SM_BLOCK

    // ---- combine the 4 kv-quarter partials through LDS ----
    __syncthreads();  // P buffers dead everywhere; Of region may now overwrite them
#pragma unroll
    for (int qs = 0; qs < 2; ++qs) {
#pragma unroll
        for (int dt = 0; dt < 4; ++dt)
#pragma unroll
            for (int r = 0; r < 4; ++r)
                *(float*)(lds + wid * 8320 + (qs * 16 + l4 * 4 + r) * 260 +
                          (dt * 16 + l15) * 4) = o[qs][dt][r];
        if (l4 == 0) {
            float2 v; v.x = mrun[qs]; v.y = lrun[qs];
            *(float2*)(lds + 33280 + (wid * 32 + qs * 16 + l15) * 8) = v;
        }
    }
    __syncthreads();
    {
        int q = threadIdx.x >> 3;
        int d0 = (threadIdx.x & 7) * 8;
        float mW[4], lW[4];
#pragma unroll
        for (int w = 0; w < 4; ++w) {
            float2 v = *(const float2*)(lds + 33280 + (w * 32 + q) * 8);
            mW[w] = v.x; lW[w] = v.y;
        }
        float m = fmaxf(fmaxf(mW[0], mW[1]), fmaxf(mW[2], mW[3]));
        float wg[4]; float lsum = 0.f;
#pragma unroll
        for (int w = 0; w < 4; ++w) { wg[w] = exp2f(mW[w] - m); lsum += lW[w] * wg[w]; }
        float inv = 1.0f / lsum;
        union { short s[8]; int4 v; } ou;
#pragma unroll
        for (int j = 0; j < 8; ++j) {
            float acc = 0.f;
#pragma unroll
            for (int w = 0; w < 4; ++w)
                acc += wg[w] * *(const float*)(lds + w * 8320 + q * 260 + (d0 + j) * 4);
            ou.s[j] = (short)f2bf(acc * inv);
        }
        *(int4*)(AO + ((size_t)b * 2048 + q0 + q) * 512 + h * 64 + d0) = ou.v;
    }
}

// ---------------- launcher ----------------
extern "C" void kernel_launch(void* const* d_in, const int* in_sizes, int n_in,
                              void* d_out, int out_size, void* d_ws, size_t ws_size,
                              hipStream_t stream) {
    const float* q  = (const float*)d_in[0];
    const float* k  = (const float*)d_in[1];
    const float* v  = (const float*)d_in[2];
    const int*   gm = (const int*)d_in[3];
    const float* Wq = (const float*)d_in[4];  const float* bq = (const float*)d_in[5];
    const float* Wk = (const float*)d_in[6];  const float* bk = (const float*)d_in[7];
    const float* Wv = (const float*)d_in[8];  const float* bv = (const float*)d_in[9];
    const float* Wo = (const float*)d_in[10]; const float* bo = (const float*)d_in[11];

    char* ws = (char*)d_ws;
    short* Xq  = (short*)(ws + 0);
    short* Xk  = (short*)(ws + 8388608);
    short* Xv  = (short*)(ws + 16777216);
    short* WqT = (short*)(ws + 25165824);
    short* WkT = (short*)(ws + 25690112);
    short* WvT = (short*)(ws + 26214400);
    short* WoT = (short*)(ws + 26738688);
    short* Qw  = (short*)(ws + 27262976);    // [b,h,tok,d] (pre-scaled)
    short* Kw  = (short*)(ws + 35651584);    // [b,h,tok,d]
    short* VTw = (short*)(ws + 44040192);    // [b,h,d,tok]
    short* AO  = (short*)(ws + 52428800);    // attn out [b,tok,h*64+d]
    unsigned long long* MP = (unsigned long long*)(ws + 60817408);

    cvt_x_kernel<<<dim3(4096, 3), 256, 0, stream>>>(q, k, v, Xq, Xk, Xv);
    cvt_wt_kernel<<<dim3(128, 4), 256, 0, stream>>>(Wq, Wk, Wv, Wo, WqT, WkT, WvT, WoT);
    pack_mask_kernel<<<dim3(2048), 256, 0, stream>>>(gm, MP);

    gemm_kernel<<<dim3(4, 64), 256, 0, stream>>>(Xq, WqT, bq, Qw, 0);
    gemm_kernel<<<dim3(4, 64), 256, 0, stream>>>(Xk, WkT, bk, Kw, 1);
    gemm_kernel<<<dim3(4, 64), 256, 0, stream>>>(Xv, WvT, bv, VTw, 2);

    attn_kernel<<<dim3(64, 8, 4), 256, 0, stream>>>(Qw, Kw, VTw, MP, AO);

    gemm_kernel<<<dim3(4, 64), 256, 0, stream>>>(AO, WoT, bo, (void*)d_out, 3);
}